// Round 1
// baseline (9205.607 us; speedup 1.0000x reference)
//
#include <hip/hip_runtime.h>

// Problem: B=128, T=512, I=512, H=2048, O=512, steps = T-2 = 510.
// Persistent-RNN: W_hh lives in VGPR MFMA B-fragments across 256 blocks
// (8 row-groups x 32 col-groups). Per-row-group 32-block software barrier
// (device-scope atomics + agent fences) per timestep; h broadcast via d_ws.
#define Bsz 128
#define Tsz 512
#define Isz 512
#define Hsz 2048
#define Osz 512
#define STEPS 510

typedef short short8 __attribute__((ext_vector_type(8)));
typedef float floatx4 __attribute__((ext_vector_type(4)));

// fp32 -> bf16 round-to-nearest-even (finite inputs only)
__device__ __forceinline__ unsigned short f2bf(float f) {
  unsigned int u = __builtin_bit_cast(unsigned int, f);
  u += 0x7FFFu + ((u >> 16) & 1u);
  return (unsigned short)(u >> 16);
}

// async global->LDS, 16B per lane; LDS dest is wave-uniform base + lane*16
__device__ __forceinline__ void gload_lds16(const void* g, void* l) {
  __builtin_amdgcn_global_load_lds(
      (const __attribute__((address_space(1))) void*)g,
      (__attribute__((address_space(3))) void*)l, 16, 0, 0);
}

// LDS strides (shorts). +8 pad => row stride 4112 B => 4-bank shift/row
// => 2-way conflict on ds_read_b128 A-frags (free per m136).
#define HSTR 2056
#define XSTR 520
#define XBUF (16 * XSTR)

__global__ __launch_bounds__(256, 1)
void rnn_kernel(const float* __restrict__ x, const float* __restrict__ h0v,
                const float* __restrict__ W_ih, const float* __restrict__ b_ih,
                const float* __restrict__ W_hh, const float* __restrict__ b_hh,
                unsigned short* __restrict__ hbuf,  // [2][128][2048] bf16
                float* __restrict__ hfinal,         // [128][2048] f32
                unsigned int* __restrict__ flags)   // [8][32] counters
{
  __shared__ short h_lds[16 * HSTR];      // 65792 B
  __shared__ short x_lds[2 * XBUF];       // 33280 B (double buffered)
  __shared__ float red_lds[4 * 16 * 64];  // 16384 B (k-split partials)
  __shared__ int pad_lds[16];

  const int tid = threadIdx.x;
  const int lane = tid & 63;
  const int wv = tid >> 6;    // wave 0..3 -> k-quarter
  const int m16 = lane & 15;  // MFMA: A row / B col / C col
  const int quad = lane >> 4;
  const int rg = blockIdx.x & 7;   // row group (bid%8 -> XCD locality)
  const int cg = blockIdx.x >> 3;  // col group 0..31
  const int b0 = rg * 16;
  const int c0 = cg * 64;
  const int kq = wv * 512;   // W_hh k-range for this wave
  const int kqx = wv * 128;  // W_ih k-range

  // ---- one-time: weight slices -> bf16 B-fragments in registers ----
  // B-frag layout: lane holds B[k = quad*8 + j][n = lane&15]
  short8 wf[16][4];  // [kchunk within quarter][ntile]
  short8 wih[4][4];
#pragma unroll
  for (int nt = 0; nt < 4; ++nt) {
    const int wrow = c0 + nt * 16 + m16;  // W row = output col j
    const float* base = W_hh + (size_t)wrow * Hsz + kq + quad * 8;
#pragma unroll
    for (int kc = 0; kc < 16; ++kc) {
      short8 v;
#pragma unroll
      for (int j = 0; j < 8; ++j) v[j] = (short)f2bf(base[kc * 32 + j]);
      wf[kc][nt] = v;
    }
    const float* basex = W_ih + (size_t)wrow * Isz + kqx + quad * 8;
#pragma unroll
    for (int kc = 0; kc < 4; ++kc) {
      short8 v;
#pragma unroll
      for (int j = 0; j < 8; ++j) v[j] = (short)f2bf(basex[kc * 32 + j]);
      wih[kc][nt] = v;
    }
  }

  // reduce-phase assignment: thread handles (row=tid>>4, 4 cols at 4*(tid&15))
  const int rrow = tid >> 4;
  const int rcb = (tid & 15) * 4;
  float bias[4];
#pragma unroll
  for (int i = 0; i < 4; ++i) bias[i] = b_ih[c0 + rcb + i] + b_hh[c0 + rcb + i];

  if (tid < 16)
    pad_lds[tid] = (int)x[(size_t)(b0 + tid) * (Tsz * Isz) + (size_t)(Tsz - 1) * Isz];

  // h_0 = h0 broadcast to the 16 rows (bf16 in LDS)
  for (int k = tid; k < Hsz; k += 256) {
    const short v = (short)f2bf(h0v[k]);
#pragma unroll
    for (int r = 0; r < 16; ++r) h_lds[r * HSTR + k] = v;
  }

  // stage x_0 into parity-0 x buffer
  {
    const float* xp = x + (size_t)(b0 + rrow) * (Tsz * Isz);
    short* xb = x_lds + rrow * XSTR;
#pragma unroll
    for (int it = 0; it < 8; ++it) {
      const int i0 = it * 64 + (tid & 15) * 4;
      const float4 v = *reinterpret_cast<const float4*>(xp + i0);
      unsigned long long pk = (unsigned long long)f2bf(v.x) |
                              ((unsigned long long)f2bf(v.y) << 16) |
                              ((unsigned long long)f2bf(v.z) << 32) |
                              ((unsigned long long)f2bf(v.w) << 48);
      *reinterpret_cast<unsigned long long*>(xb + i0) = pk;
    }
  }

  unsigned int* myflag = flags + rg * 32;

  for (int t = 0; t < STEPS; ++t) {
    const bool have_next = (t + 1) < STEPS;

    // phase A: issue next-step x loads early (overlap with poll + h DMA)
    float4 xv[8];
    if (have_next) {
      const float* xp = x + (size_t)(b0 + rrow) * (Tsz * Isz) + (size_t)(t + 1) * Isz;
#pragma unroll
      for (int it = 0; it < 8; ++it)
        xv[it] = *reinterpret_cast<const float4*>(xp + it * 64 + (tid & 15) * 4);
    }

    if (t > 0) {
      // wait until all 32 blocks of this row-group posted h_t
      if (tid == 0) {
        const unsigned int target = (unsigned int)(32 * t);
        while (__hip_atomic_load(myflag, __ATOMIC_RELAXED, __HIP_MEMORY_SCOPE_AGENT) < target)
          __builtin_amdgcn_s_sleep(2);
      }
      __syncthreads();
      __builtin_amdgcn_fence(__ATOMIC_ACQUIRE, "agent");
      // DMA h_t [16 rows x 2048] bf16 -> LDS (4 rows per wave, 1KB chunks)
      const unsigned short* hsrc = hbuf + (size_t)(t & 1) * (Bsz * Hsz);
#pragma unroll
      for (int r2 = 0; r2 < 4; ++r2) {
        const int row = wv * 4 + r2;
#pragma unroll
        for (int ch = 0; ch < 4; ++ch) {
          gload_lds16(hsrc + (size_t)(b0 + row) * Hsz + ch * 512 + lane * 8,
                      &h_lds[row * HSTR + ch * 512]);
        }
      }
    }

    // phase B: convert + stage x_{t+1} (overlaps h DMA latency)
    if (have_next) {
      short* xb = x_lds + ((t + 1) & 1) * XBUF + rrow * XSTR;
#pragma unroll
      for (int it = 0; it < 8; ++it) {
        const int i0 = it * 64 + (tid & 15) * 4;
        unsigned long long pk = (unsigned long long)f2bf(xv[it].x) |
                                ((unsigned long long)f2bf(xv[it].y) << 16) |
                                ((unsigned long long)f2bf(xv[it].z) << 32) |
                                ((unsigned long long)f2bf(xv[it].w) << 48);
        *reinterpret_cast<unsigned long long*>(xb + i0) = pk;
      }
    }

    __syncthreads();  // drains h DMA (vmcnt) + x LDS writes

    // ---- MFMA: z-partial[16x64] for this wave's k-quarter ----
    floatx4 acc[4];
#pragma unroll
    for (int nt = 0; nt < 4; ++nt) {
      floatx4 zero = {0.f, 0.f, 0.f, 0.f};
      acc[nt] = zero;
    }
    {
      const short* xbase = x_lds + (t & 1) * XBUF + m16 * XSTR + kqx + quad * 8;
#pragma unroll
      for (int kc = 0; kc < 4; ++kc) {
        const short8 a = *reinterpret_cast<const short8*>(xbase + kc * 32);
#pragma unroll
        for (int nt = 0; nt < 4; ++nt)
          acc[nt] = __builtin_amdgcn_mfma_f32_16x16x32_bf16(a, wih[kc][nt], acc[nt], 0, 0, 0);
      }
      const short* hbase = h_lds + m16 * HSTR + kq + quad * 8;
#pragma unroll
      for (int kc = 0; kc < 16; ++kc) {
        const short8 a = *reinterpret_cast<const short8*>(hbase + kc * 32);
#pragma unroll
        for (int nt = 0; nt < 4; ++nt)
          acc[nt] = __builtin_amdgcn_mfma_f32_16x16x32_bf16(a, wf[kc][nt], acc[nt], 0, 0, 0);
      }
    }

    // partials -> LDS (C layout: row = quad*4+reg, col = nt*16 + lane&15)
#pragma unroll
    for (int nt = 0; nt < 4; ++nt)
#pragma unroll
      for (int i = 0; i < 4; ++i)
        red_lds[wv * 1024 + (quad * 4 + i) * 64 + nt * 16 + m16] = acc[nt][i];

    __syncthreads();

    // ---- reduce 4 k-partials + bias, tanh, store h_{t+1}, capture pad ----
    {
      float4 z = {0.f, 0.f, 0.f, 0.f};
#pragma unroll
      for (int ww = 0; ww < 4; ++ww) {
        const float4 p = *reinterpret_cast<const float4*>(&red_lds[ww * 1024 + rrow * 64 + rcb]);
        z.x += p.x; z.y += p.y; z.z += p.z; z.w += p.w;
      }
      const float t0 = tanhf(z.x + bias[0]);
      const float t1 = tanhf(z.y + bias[1]);
      const float t2 = tanhf(z.z + bias[2]);
      const float t3 = tanhf(z.w + bias[3]);
      unsigned long long pk = (unsigned long long)f2bf(t0) |
                              ((unsigned long long)f2bf(t1) << 16) |
                              ((unsigned long long)f2bf(t2) << 32) |
                              ((unsigned long long)f2bf(t3) << 48);
      unsigned short* hd = hbuf + (size_t)((t + 1) & 1) * (Bsz * Hsz) +
                           (size_t)(b0 + rrow) * Hsz + c0 + rcb;
      *reinterpret_cast<unsigned long long*>(hd) = pk;
      if (pad_lds[rrow] == t) {
        float4 o;
        o.x = t0; o.y = t1; o.z = t2; o.w = t3;
        *reinterpret_cast<float4*>(&hfinal[(size_t)(b0 + rrow) * Hsz + c0 + rcb]) = o;
      }
    }

    __syncthreads();  // all waves' h stores drained (vmcnt) before posting

    if (have_next && tid == 0) {
      __builtin_amdgcn_fence(__ATOMIC_RELEASE, "agent");  // flush L2 -> L3
      __hip_atomic_fetch_add(myflag, 1u, __ATOMIC_RELAXED, __HIP_MEMORY_SCOPE_AGENT);
    }
  }
}

// out[b][o] = hfinal[b][:] . W_fc[o][:] + b_fc[o]; 8 b-tiles x 32 o-tiles
__global__ __launch_bounds__(64)
void fc_kernel(const float* __restrict__ hfinal, const float* __restrict__ W_fc,
               const float* __restrict__ b_fc, float* __restrict__ out) {
  const int lane = threadIdx.x & 63;
  const int m16 = lane & 15;
  const int quad = lane >> 4;
  const int b0 = (blockIdx.x & 7) * 16;
  const int o0 = (blockIdx.x >> 3) * 16;
  floatx4 acc = {0.f, 0.f, 0.f, 0.f};
  const float* ap = hfinal + (size_t)(b0 + m16) * Hsz + quad * 8;
  const float* bp = W_fc + (size_t)(o0 + m16) * Hsz + quad * 8;
#pragma unroll 4
  for (int kc = 0; kc < 64; ++kc) {
    short8 a, b;
#pragma unroll
    for (int j = 0; j < 8; ++j) a[j] = (short)f2bf(ap[kc * 32 + j]);
#pragma unroll
    for (int j = 0; j < 8; ++j) b[j] = (short)f2bf(bp[kc * 32 + j]);
    acc = __builtin_amdgcn_mfma_f32_16x16x32_bf16(a, b, acc, 0, 0, 0);
  }
  const float bias = b_fc[o0 + m16];
#pragma unroll
  for (int i = 0; i < 4; ++i)
    out[(size_t)(b0 + quad * 4 + i) * Osz + o0 + m16] = acc[i] + bias;
}

__global__ void zero_flags(unsigned int* f) { f[threadIdx.x] = 0u; }

extern "C" void kernel_launch(void* const* d_in, const int* in_sizes, int n_in,
                              void* d_out, int out_size, void* d_ws, size_t ws_size,
                              hipStream_t stream) {
  const float* x = (const float*)d_in[0];
  const float* h0 = (const float*)d_in[1];
  const float* W_ih = (const float*)d_in[2];
  const float* b_ih = (const float*)d_in[3];
  const float* W_hh = (const float*)d_in[4];
  const float* b_hh = (const float*)d_in[5];
  const float* W_fc = (const float*)d_in[6];
  const float* b_fc = (const float*)d_in[7];
  float* out = (float*)d_out;

  char* ws = (char*)d_ws;
  unsigned short* hbuf = (unsigned short*)ws;           // 1 MiB (2x128x2048 bf16)
  float* hfinal = (float*)(ws + (1u << 20));            // 1 MiB
  unsigned int* flags = (unsigned int*)(ws + (2u << 20));  // 1 KiB (re-zeroed per launch)

  zero_flags<<<1, 256, 0, stream>>>(flags);
  rnn_kernel<<<256, 256, 0, stream>>>(x, h0, W_ih, b_ih, W_hh, b_hh, hbuf, hfinal, flags);
  fc_kernel<<<256, 64, 0, stream>>>(hfinal, W_fc, b_fc, out);
}

// Round 3
// 2318.120 us; speedup vs baseline: 3.9712x; 3.9712x over previous
//
#include <hip/hip_runtime.h>

// Problem: B=128, T=512, I=512, H=2048, O=512, steps = T-2 = 510.
// Persistent-RNN: W_hh lives in VGPR/AGPR MFMA B-fragments across 256 blocks
// (8 row-groups x 32 col-groups). Per-row-group 32-block software barrier
// per timestep; h broadcast via d_ws.
//
// R3 = R2 with the compile fix: global_load_lds aux must be an immediate ->
// template parameter. Sync path has NO fences: h stores are device-coherent
// (relaxed agent atomic stores -> sc0 sc1, write-through to L3); flag posted
// with relaxed agent fetch_add after __syncthreads' vmcnt(0) drain; h loads
// use global_load_lds with CPol aux=0x11 (SC0|SC1) to read coherently from
// L3, bypassing stale L2. Removes per-step buffer_wbl2/buffer_inv walks.
#define Bsz 128
#define Tsz 512
#define Isz 512
#define Hsz 2048
#define Osz 512
#define STEPS 510

typedef short short8 __attribute__((ext_vector_type(8)));
typedef float floatx4 __attribute__((ext_vector_type(4)));

// fp32 -> bf16 round-to-nearest-even (finite inputs only)
__device__ __forceinline__ unsigned short f2bf(float f) {
  unsigned int u = __builtin_bit_cast(unsigned int, f);
  u += 0x7FFFu + ((u >> 16) & 1u);
  return (unsigned short)(u >> 16);
}

// async global->LDS, 16B per lane; LDS dest is wave-uniform base + lane*16
// AUX = CPol immediate: 0x11 = SC0|SC1 (device-coherent: read L3, bypass L1/L2)
template <int AUX>
__device__ __forceinline__ void gload_lds16(const void* g, void* l) {
  __builtin_amdgcn_global_load_lds(
      (const __attribute__((address_space(1))) void*)g,
      (__attribute__((address_space(3))) void*)l, 16, 0, AUX);
}

// LDS strides (shorts). +8 pad => row stride 4112 B => 4-bank shift/row
// => 2-way conflict on ds_read_b128 A-frags (free per m136).
#define HSTR 2056
#define XSTR 520
#define XBUF (16 * XSTR)

__global__ __launch_bounds__(256, 1)
void rnn_kernel(const float* __restrict__ x, const float* __restrict__ h0v,
                const float* __restrict__ W_ih, const float* __restrict__ b_ih,
                const float* __restrict__ W_hh, const float* __restrict__ b_hh,
                unsigned short* __restrict__ hbuf,  // [2][128][2048] bf16
                float* __restrict__ hfinal,         // [128][2048] f32
                unsigned int* __restrict__ flags)   // [8][32] counters
{
  __shared__ short h_lds[16 * HSTR];      // 65792 B
  __shared__ short x_lds[2 * XBUF];       // 33280 B (double buffered)
  __shared__ float red_lds[4 * 16 * 64];  // 16384 B (k-split partials)
  __shared__ int pad_lds[16];

  const int tid = threadIdx.x;
  const int lane = tid & 63;
  const int wv = tid >> 6;    // wave 0..3 -> k-quarter
  const int m16 = lane & 15;  // MFMA: A row / B col / C col
  const int quad = lane >> 4;
  const int rg = blockIdx.x & 7;   // row group (bid%8 -> XCD locality)
  const int cg = blockIdx.x >> 3;  // col group 0..31
  const int b0 = rg * 16;
  const int c0 = cg * 64;
  const int kq = wv * 512;   // W_hh k-range for this wave
  const int kqx = wv * 128;  // W_ih k-range

  // ---- one-time: weight slices -> bf16 B-fragments in registers ----
  // B-frag layout: lane holds B[k = quad*8 + j][n = lane&15]
  short8 wf[16][4];  // [kchunk within quarter][ntile]
  short8 wih[4][4];
#pragma unroll
  for (int nt = 0; nt < 4; ++nt) {
    const int wrow = c0 + nt * 16 + m16;  // W row = output col j
    const float* base = W_hh + (size_t)wrow * Hsz + kq + quad * 8;
#pragma unroll
    for (int kc = 0; kc < 16; ++kc) {
      short8 v;
#pragma unroll
      for (int j = 0; j < 8; ++j) v[j] = (short)f2bf(base[kc * 32 + j]);
      wf[kc][nt] = v;
    }
    const float* basex = W_ih + (size_t)wrow * Isz + kqx + quad * 8;
#pragma unroll
    for (int kc = 0; kc < 4; ++kc) {
      short8 v;
#pragma unroll
      for (int j = 0; j < 8; ++j) v[j] = (short)f2bf(basex[kc * 32 + j]);
      wih[kc][nt] = v;
    }
  }

  // reduce-phase assignment: thread handles (row=tid>>4, 4 cols at 4*(tid&15))
  const int rrow = tid >> 4;
  const int rcb = (tid & 15) * 4;
  float bias[4];
#pragma unroll
  for (int i = 0; i < 4; ++i) bias[i] = b_ih[c0 + rcb + i] + b_hh[c0 + rcb + i];

  if (tid < 16)
    pad_lds[tid] = (int)x[(size_t)(b0 + tid) * (Tsz * Isz) + (size_t)(Tsz - 1) * Isz];

  // h_0 = h0 broadcast to the 16 rows (bf16 in LDS)
  for (int k = tid; k < Hsz; k += 256) {
    const short v = (short)f2bf(h0v[k]);
#pragma unroll
    for (int r = 0; r < 16; ++r) h_lds[r * HSTR + k] = v;
  }

  // stage x_0 into parity-0 x buffer
  {
    const float* xp = x + (size_t)(b0 + rrow) * (Tsz * Isz);
    short* xb = x_lds + rrow * XSTR;
#pragma unroll
    for (int it = 0; it < 8; ++it) {
      const int i0 = it * 64 + (tid & 15) * 4;
      const float4 v = *reinterpret_cast<const float4*>(xp + i0);
      unsigned long long pk = (unsigned long long)f2bf(v.x) |
                              ((unsigned long long)f2bf(v.y) << 16) |
                              ((unsigned long long)f2bf(v.z) << 32) |
                              ((unsigned long long)f2bf(v.w) << 48);
      *reinterpret_cast<unsigned long long*>(xb + i0) = pk;
    }
  }

  unsigned int* myflag = flags + rg * 32;

  for (int t = 0; t < STEPS; ++t) {
    const bool have_next = (t + 1) < STEPS;

    // phase A: issue next-step x loads early (overlap with poll + h DMA)
    float4 xv[8];
    if (have_next) {
      const float* xp = x + (size_t)(b0 + rrow) * (Tsz * Isz) + (size_t)(t + 1) * Isz;
#pragma unroll
      for (int it = 0; it < 8; ++it)
        xv[it] = *reinterpret_cast<const float4*>(xp + it * 64 + (tid & 15) * 4);
    }

    if (t > 0) {
      // wait until all 32 blocks of this row-group posted h_t.
      // No acquire fence needed: h loads below bypass L1/L2 (CPol sc0|sc1)
      // and read the L3 coherence point directly.
      if (tid == 0) {
        const unsigned int target = (unsigned int)(32 * t);
        while (__hip_atomic_load(myflag, __ATOMIC_RELAXED, __HIP_MEMORY_SCOPE_AGENT) < target)
          __builtin_amdgcn_s_sleep(2);
      }
      __syncthreads();
      // DMA h_t [16 rows x 2048] bf16 -> LDS (4 rows per wave, 1KB chunks),
      // device-coherent (aux=0x11)
      const unsigned short* hsrc = hbuf + (size_t)(t & 1) * (Bsz * Hsz);
#pragma unroll
      for (int r2 = 0; r2 < 4; ++r2) {
        const int row = wv * 4 + r2;
#pragma unroll
        for (int ch = 0; ch < 4; ++ch) {
          gload_lds16<0x11>(hsrc + (size_t)(b0 + row) * Hsz + ch * 512 + lane * 8,
                            &h_lds[row * HSTR + ch * 512]);
        }
      }
    }

    // phase B: convert + stage x_{t+1} (overlaps h DMA latency)
    if (have_next) {
      short* xb = x_lds + ((t + 1) & 1) * XBUF + rrow * XSTR;
#pragma unroll
      for (int it = 0; it < 8; ++it) {
        const int i0 = it * 64 + (tid & 15) * 4;
        unsigned long long pk = (unsigned long long)f2bf(xv[it].x) |
                                ((unsigned long long)f2bf(xv[it].y) << 16) |
                                ((unsigned long long)f2bf(xv[it].z) << 32) |
                                ((unsigned long long)f2bf(xv[it].w) << 48);
        *reinterpret_cast<unsigned long long*>(xb + i0) = pk;
      }
    }

    __syncthreads();  // drains h DMA (vmcnt) + x LDS writes

    // ---- MFMA: z-partial[16x64] for this wave's k-quarter ----
    floatx4 acc[4];
#pragma unroll
    for (int nt = 0; nt < 4; ++nt) {
      floatx4 zero = {0.f, 0.f, 0.f, 0.f};
      acc[nt] = zero;
    }
    {
      const short* xbase = x_lds + (t & 1) * XBUF + m16 * XSTR + kqx + quad * 8;
#pragma unroll
      for (int kc = 0; kc < 4; ++kc) {
        const short8 a = *reinterpret_cast<const short8*>(xbase + kc * 32);
#pragma unroll
        for (int nt = 0; nt < 4; ++nt)
          acc[nt] = __builtin_amdgcn_mfma_f32_16x16x32_bf16(a, wih[kc][nt], acc[nt], 0, 0, 0);
      }
      const short* hbase = h_lds + m16 * HSTR + kq + quad * 8;
#pragma unroll
      for (int kc = 0; kc < 16; ++kc) {
        const short8 a = *reinterpret_cast<const short8*>(hbase + kc * 32);
#pragma unroll
        for (int nt = 0; nt < 4; ++nt)
          acc[nt] = __builtin_amdgcn_mfma_f32_16x16x32_bf16(a, wf[kc][nt], acc[nt], 0, 0, 0);
      }
    }

    // partials -> LDS (C layout: row = quad*4+reg, col = nt*16 + lane&15)
#pragma unroll
    for (int nt = 0; nt < 4; ++nt)
#pragma unroll
      for (int i = 0; i < 4; ++i)
        red_lds[wv * 1024 + (quad * 4 + i) * 64 + nt * 16 + m16] = acc[nt][i];

    __syncthreads();

    // ---- reduce 4 k-partials + bias, tanh, store h_{t+1}, capture pad ----
    {
      float4 z = {0.f, 0.f, 0.f, 0.f};
#pragma unroll
      for (int ww = 0; ww < 4; ++ww) {
        const float4 p = *reinterpret_cast<const float4*>(&red_lds[ww * 1024 + rrow * 64 + rcb]);
        z.x += p.x; z.y += p.y; z.z += p.z; z.w += p.w;
      }
      const float t0 = tanhf(z.x + bias[0]);
      const float t1 = tanhf(z.y + bias[1]);
      const float t2 = tanhf(z.z + bias[2]);
      const float t3 = tanhf(z.w + bias[3]);
      unsigned long long pk = (unsigned long long)f2bf(t0) |
                              ((unsigned long long)f2bf(t1) << 16) |
                              ((unsigned long long)f2bf(t2) << 32) |
                              ((unsigned long long)f2bf(t3) << 48);
      unsigned short* hd = hbuf + (size_t)((t + 1) & 1) * (Bsz * Hsz) +
                           (size_t)(b0 + rrow) * Hsz + c0 + rcb;
      // device-coherent store: write-through to L3, never dirty in L2
      __hip_atomic_store(reinterpret_cast<unsigned long long*>(hd), pk,
                         __ATOMIC_RELAXED, __HIP_MEMORY_SCOPE_AGENT);
      if (pad_lds[rrow] == t) {
        float4 o;
        o.x = t0; o.y = t1; o.z = t2; o.w = t3;
        *reinterpret_cast<float4*>(&hfinal[(size_t)(b0 + rrow) * Hsz + c0 + rcb]) = o;
      }
    }

    __syncthreads();  // vmcnt(0) drain: h stores complete at L3 before post

    if (have_next && tid == 0) {
      // relaxed is safe: prior coherent stores already drained to L3 by the
      // barrier's vmcnt(0); no buffer_wbl2 emitted.
      __hip_atomic_fetch_add(myflag, 1u, __ATOMIC_RELAXED, __HIP_MEMORY_SCOPE_AGENT);
    }
  }
}

// out[b][o] = hfinal[b][:] . W_fc[o][:] + b_fc[o]; 8 b-tiles x 32 o-tiles
__global__ __launch_bounds__(64)
void fc_kernel(const float* __restrict__ hfinal, const float* __restrict__ W_fc,
               const float* __restrict__ b_fc, float* __restrict__ out) {
  const int lane = threadIdx.x & 63;
  const int m16 = lane & 15;
  const int quad = lane >> 4;
  const int b0 = (blockIdx.x & 7) * 16;
  const int o0 = (blockIdx.x >> 3) * 16;
  floatx4 acc = {0.f, 0.f, 0.f, 0.f};
  const float* ap = hfinal + (size_t)(b0 + m16) * Hsz + quad * 8;
  const float* bp = W_fc + (size_t)(o0 + m16) * Hsz + quad * 8;
#pragma unroll 4
  for (int kc = 0; kc < 64; ++kc) {
    short8 a, b;
#pragma unroll
    for (int j = 0; j < 8; ++j) a[j] = (short)f2bf(ap[kc * 32 + j]);
#pragma unroll
    for (int j = 0; j < 8; ++j) b[j] = (short)f2bf(bp[kc * 32 + j]);
    acc = __builtin_amdgcn_mfma_f32_16x16x32_bf16(a, b, acc, 0, 0, 0);
  }
  const float bias = b_fc[o0 + m16];
#pragma unroll
  for (int i = 0; i < 4; ++i)
    out[(size_t)(b0 + quad * 4 + i) * Osz + o0 + m16] = acc[i] + bias;
}

__global__ void zero_flags(unsigned int* f) { f[threadIdx.x] = 0u; }

extern "C" void kernel_launch(void* const* d_in, const int* in_sizes, int n_in,
                              void* d_out, int out_size, void* d_ws, size_t ws_size,
                              hipStream_t stream) {
  const float* x = (const float*)d_in[0];
  const float* h0 = (const float*)d_in[1];
  const float* W_ih = (const float*)d_in[2];
  const float* b_ih = (const float*)d_in[3];
  const float* W_hh = (const float*)d_in[4];
  const float* b_hh = (const float*)d_in[5];
  const float* W_fc = (const float*)d_in[6];
  const float* b_fc = (const float*)d_in[7];
  float* out = (float*)d_out;

  char* ws = (char*)d_ws;
  unsigned short* hbuf = (unsigned short*)ws;           // 1 MiB (2x128x2048 bf16)
  float* hfinal = (float*)(ws + (1u << 20));            // 1 MiB
  unsigned int* flags = (unsigned int*)(ws + (2u << 20));  // 1 KiB (re-zeroed per launch)

  zero_flags<<<1, 256, 0, stream>>>(flags);
  rnn_kernel<<<256, 256, 0, stream>>>(x, h0, W_ih, b_ih, W_hh, b_hh, hbuf, hfinal, flags);
  fc_kernel<<<256, 64, 0, stream>>>(hfinal, W_fc, b_fc, out);
}